// Round 2
// baseline (7571.268 us; speedup 1.0000x reference)
//
#include <hip/hip_runtime.h>
#include <hip/hip_bf16.h>

// EGNN layer, f32 in/out (per reference dtypes), f32 internal math.
constexpr int ND  = 128;   // node dim
constexpr int HD  = 256;   // hidden dim
constexpr int ED  = 64;    // edge dim
constexpr int MIN_DIM = 2 * ND + ED;  // 320
constexpr int RT  = 16;    // edges per block tile

__device__ __forceinline__ float silu_f(float v) { return v / (1.0f + __expf(-v)); }

__global__ __launch_bounds__(256) void egnn_edge_kernel(
    const float* __restrict__ h,
    const float* __restrict__ x,
    const int* __restrict__ eidx,          // [2, E] flat (int64 converted to int32 by harness)
    const float* __restrict__ dist,
    const float* __restrict__ Wn1, const float* __restrict__ bn1,
    const float* __restrict__ Wn2, const float* __restrict__ bn2,
    const float* __restrict__ Wc1, const float* __restrict__ bc1,
    const float* __restrict__ Wc2,
    const float* __restrict__ We1, const float* __restrict__ be1,
    const float* __restrict__ We2, const float* __restrict__ be2,
    float* __restrict__ h_agg, float* __restrict__ x_agg,
    int n_edges)
{
    __shared__ float m_sh[RT * MIN_DIM];   // 16x320 f32 = 20 KB
    __shared__ float hid_sh[RT * HD];      // 16 KB
    __shared__ float chid_sh[RT * HD];     // 16 KB
    __shared__ float se_sh[RT * ED];       // 4 KB
    __shared__ int   s_sh[RT];
    __shared__ int   d_sh[RT];
    __shared__ float dist_sh[RT];

    const int tid = threadIdx.x;
    const int e0  = blockIdx.x * RT;
    const int nv  = min(RT, n_edges - e0);  // valid edges in this tile

    if (tid < RT) {
        int e = e0 + min(tid, nv - 1);      // clamp (keeps gathers in-bounds)
        s_sh[tid]    = eidx[e];
        d_sh[tid]    = eidx[n_edges + e];
        dist_sh[tid] = dist[e];
    }
    __syncthreads();

    // --- gather h[src], h[dst] into m_sh[:, 0:256] via float4 ---
    {
        const float4* h4 = (const float4*)h;       // 32 float4 per node row
        for (int idx = tid; idx < RT * 64; idx += 256) {
            int r = idx >> 6, c = idx & 63;        // c: 0..31 src, 32..63 dst
            int node = (c < 32) ? s_sh[r] : d_sh[r];
            int cc   = c & 31;
            float4 v = h4[(size_t)node * 32 + cc];
            float* dst = &m_sh[r * MIN_DIM + ((c < 32) ? 0 : ND) + cc * 4];
            dst[0] = v.x; dst[1] = v.y; dst[2] = v.z; dst[3] = v.w;
        }
    }
    // --- edge MLP layer 1: silu(dist * We1 + be1) ---
    for (int idx = tid; idx < RT * ED; idx += 256) {
        int r = idx >> 6, k = idx & 63;
        float t = fmaf(dist_sh[r], We1[k], be1[k]);
        se_sh[idx] = silu_f(t);
    }
    __syncthreads();
    // --- edge MLP layer 2: edge_attr = se @ We2 + be2 -> m_sh[:, 256:320] ---
    for (int idx = tid; idx < RT * ED; idx += 256) {
        int r = idx >> 6, j = idx & 63;
        float sum = be2[j];
        #pragma unroll 8
        for (int k = 0; k < ED; ++k)
            sum = fmaf(se_sh[r * ED + k], We2[k * ED + j], sum);
        m_sh[r * MIN_DIM + 2 * ND + j] = sum;
    }
    __syncthreads();

    // --- hid = silu(m @ Wn1 + bn1); chid = silu(m @ Wc1 + bc1) ---
    {
        const int j = tid;  // column 0..255
        float accn[RT], accc[RT];
        const float bn = bn1[j];
        const float bc = bc1[j];
        #pragma unroll
        for (int r = 0; r < RT; ++r) { accn[r] = bn; accc[r] = bc; }
        #pragma unroll 2
        for (int k = 0; k < MIN_DIM; ++k) {
            float wn = Wn1[k * HD + j];   // coalesced across threads
            float wc = Wc1[k * HD + j];
            #pragma unroll
            for (int r = 0; r < RT; ++r) {
                float mv = m_sh[r * MIN_DIM + k];  // LDS broadcast
                accn[r] = fmaf(mv, wn, accn[r]);
                accc[r] = fmaf(mv, wc, accc[r]);
            }
        }
        #pragma unroll
        for (int r = 0; r < RT; ++r) {
            hid_sh[r * HD + j]  = silu_f(accn[r]);
            chid_sh[r * HD + j] = silu_f(accc[r]);
        }
    }
    __syncthreads();

    // --- waves 0,1: m = hid @ Wn2 + bn2 ; scatter into h_agg ---
    if (tid < ND) {
        const int j = tid;
        float acc[RT];
        const float b = bn2[j];
        #pragma unroll
        for (int r = 0; r < RT; ++r) acc[r] = b;
        #pragma unroll 2
        for (int k = 0; k < HD; ++k) {
            float w = Wn2[k * ND + j];
            #pragma unroll
            for (int r = 0; r < RT; ++r)
                acc[r] = fmaf(hid_sh[r * HD + k], w, acc[r]);
        }
        for (int r = 0; r < nv; ++r)
            atomicAdd(&h_agg[(size_t)d_sh[r] * ND + j], acc[r]);
    } else {
        // --- waves 2,3: coord weight = chid @ Wc2 ; scatter into x_agg ---
        const int t2 = tid - ND;    // 0..127
        const int r  = t2 >> 3;     // 8 threads per edge
        const int l8 = t2 & 7;
        float p = 0.f;
        for (int k = l8; k < HD; k += 8)
            p = fmaf(chid_sh[r * HD + k], Wc2[k], p);
        p += __shfl_xor(p, 1);
        p += __shfl_xor(p, 2);
        p += __shfl_xor(p, 4);
        if (l8 == 0 && r < nv) {
            int s = s_sh[r], d = d_sh[r];
            #pragma unroll
            for (int c = 0; c < 3; ++c) {
                float dv = x[s * 3 + c] - x[d * 3 + c];
                atomicAdd(&x_agg[d * 3 + c], p * dv);
            }
        }
    }
}

__global__ __launch_bounds__(256) void egnn_finalize_kernel(
    const float* __restrict__ h,
    const float* __restrict__ x,
    const float* __restrict__ h_agg,
    const float* __restrict__ x_agg,
    float* __restrict__ out,
    int n_nodes)
{
    int i = blockIdx.x * 256 + threadIdx.x;
    int nh = n_nodes * ND;
    int total = nh + n_nodes * 3;
    if (i < nh) {
        out[i] = h[i] + h_agg[i];
    } else if (i < total) {
        int k = i - nh;
        out[i] = x[k] + x_agg[k];
    }
}

extern "C" void kernel_launch(void* const* d_in, const int* in_sizes, int n_in,
                              void* d_out, int out_size, void* d_ws, size_t ws_size,
                              hipStream_t stream)
{
    const float* h    = (const float*)d_in[0];
    const float* x    = (const float*)d_in[1];
    const int*   eidx = (const int*)d_in[2];
    const float* dist = (const float*)d_in[3];
    const float* Wn1  = (const float*)d_in[4];
    const float* bn1  = (const float*)d_in[5];
    const float* Wn2  = (const float*)d_in[6];
    const float* bn2  = (const float*)d_in[7];
    const float* Wc1  = (const float*)d_in[8];
    const float* bc1  = (const float*)d_in[9];
    const float* Wc2  = (const float*)d_in[10];
    const float* We1  = (const float*)d_in[11];
    const float* be1  = (const float*)d_in[12];
    const float* We2  = (const float*)d_in[13];
    const float* be2  = (const float*)d_in[14];

    const int E = in_sizes[3];           // 800000
    const int N = in_sizes[0] / ND;      // 50000

    float* h_agg = (float*)d_ws;
    float* x_agg = h_agg + (size_t)N * ND;
    size_t zero_bytes = ((size_t)N * ND + (size_t)N * 3) * sizeof(float);
    hipMemsetAsync(d_ws, 0, zero_bytes, stream);

    int tiles = (E + RT - 1) / RT;
    egnn_edge_kernel<<<tiles, 256, 0, stream>>>(
        h, x, eidx, dist, Wn1, bn1, Wn2, bn2, Wc1, bc1, Wc2,
        We1, be1, We2, be2, h_agg, x_agg, E);

    int total = N * ND + N * 3;
    egnn_finalize_kernel<<<(total + 255) / 256, 256, 0, stream>>>(
        h, x, h_agg, x_agg, (float*)d_out, N);
}

// Round 3
// 1002.672 us; speedup vs baseline: 7.5511x; 7.5511x over previous
//
#include <hip/hip_runtime.h>
#include <hip/hip_bf16.h>

typedef __attribute__((ext_vector_type(8))) short bf16x8;
typedef __attribute__((ext_vector_type(4))) float f32x4;

constexpr int ND = 128;   // node dim
constexpr int HD = 256;   // hidden dim
constexpr int ED = 64;    // edge dim
constexpr int ET = 64;    // edges per block tile
constexpr int MP = 328;   // m_sh pitch in bf16 (656B = 41*16B, odd -> bank stagger)
constexpr int HP = 264;   // hid pitch in bf16 (528B = 33*16B, odd)

__device__ __forceinline__ float silu_f(float v) { return v / (1.0f + __expf(-v)); }
__device__ __forceinline__ __hip_bfloat16 f2b(float v) { return __float2bfloat16(v); }

// ---------- prep: h -> bf16 ----------
__global__ __launch_bounds__(256) void prep_h(const float* __restrict__ h,
                                              __hip_bfloat16* __restrict__ hb, int n) {
    int i = blockIdx.x * 256 + threadIdx.x;
    if (i < n) hb[i] = f2b(h[i]);
}

// ---------- prep: weights -> bf16, swizzled to B-fragment order ----------
// B-frag for 16x16x32: lane l supplies B[k0 + (l>>4)*8 + j][n0 + (l&15)], j=0..7.
// Storage: sw[((ks*NT)+nt)*64 + lane][j] contiguous -> wave reads 1KB coalesced.
// Wn1'/Wc1' rows 256..319 are We2 @ W[256:320,:] (edge-MLP layer 2 folded in).
__global__ __launch_bounds__(256) void prep_w(
    const float* __restrict__ Wn1, const float* __restrict__ Wc1,
    const float* __restrict__ Wn2, const float* __restrict__ We2,
    __hip_bfloat16* __restrict__ Wn1s, __hip_bfloat16* __restrict__ Wc1s,
    __hip_bfloat16* __restrict__ Wn2s)
{
    int id = blockIdx.x * 256 + threadIdx.x;
    if (id < 163840) {                      // Wn1s / Wc1s: 10 ks * 16 nt * 64 * 8
        int e = id;
        const float* W = Wn1; __hip_bfloat16* out = Wn1s;
        if (id >= 81920) { e -= 81920; W = Wc1; out = Wc1s; }
        int j = e & 7, lane = (e >> 3) & 63, nt = (e >> 9) & 15, ks = e >> 13;
        int k = ks * 32 + (lane >> 4) * 8 + j;
        int n = nt * 16 + (lane & 15);
        float v;
        if (k < 2 * ND) v = W[k * HD + n];
        else {
            int t = k - 2 * ND; v = 0.f;
            for (int u = 0; u < ED; ++u) v += We2[t * ED + u] * W[(2 * ND + u) * HD + n];
        }
        out[e] = f2b(v);
    } else if (id < 196608) {               // Wn2s: 8 ks * 8 nt * 64 * 8
        int e = id - 163840;
        int j = e & 7, lane = (e >> 3) & 63, nt = (e >> 9) & 7, ks = e >> 12;
        int k = ks * 32 + (lane >> 4) * 8 + j;
        int n = nt * 16 + (lane & 15);
        Wn2s[e] = f2b(Wn2[k * ND + n]);
    }
}

// ---------- prep: fold be2 @ W[256:320,:] into biases ----------
__global__ __launch_bounds__(256) void prep_bias(
    const float* __restrict__ bn1, const float* __restrict__ bc1,
    const float* __restrict__ Wn1, const float* __restrict__ Wc1,
    const float* __restrict__ be2,
    float* __restrict__ bn1p, float* __restrict__ bc1p)
{
    int n = blockIdx.x * 256 + threadIdx.x;
    if (n < HD) {
        float v = bn1[n];
        for (int t = 0; t < ED; ++t) v += be2[t] * Wn1[(2 * ND + t) * HD + n];
        bn1p[n] = v;
    } else if (n < 2 * HD) {
        int m = n - HD;
        float v = bc1[m];
        for (int t = 0; t < ED; ++t) v += be2[t] * Wc1[(2 * ND + t) * HD + m];
        bc1p[m] = v;
    }
}

// ---------- main fused edge kernel ----------
__global__ __launch_bounds__(256, 3) void egnn_main(
    const __hip_bfloat16* __restrict__ hb,
    const float* __restrict__ x,
    const int* __restrict__ eidx,
    const float* __restrict__ dist,
    const __hip_bfloat16* __restrict__ Wn1s,
    const __hip_bfloat16* __restrict__ Wc1s,
    const __hip_bfloat16* __restrict__ Wn2s,
    const float* __restrict__ bn1p, const float* __restrict__ bc1p,
    const float* __restrict__ bn2,  const float* __restrict__ Wc2,
    const float* __restrict__ We1,  const float* __restrict__ be1,
    float* __restrict__ h_agg, float* __restrict__ x_agg,
    int E)
{
    __shared__ __align__(16) __hip_bfloat16 m_sh[ET * MP];  // 41984 B; later overlaid by hid
    __shared__ float dir_sh[ET * 3];
    __shared__ float coordw_sh[ET];
    __shared__ float dist_sh[ET];
    __shared__ int   sidx[ET], didx[ET];

    const int tid  = threadIdx.x;
    const int lane = tid & 63;
    const int wv   = tid >> 6;
    const int q    = lane >> 4;    // quad (0..3)
    const int lc   = lane & 15;    // lane col
    const int e0   = blockIdx.x * ET;

    if (tid < ET) {
        int e = min(e0 + tid, E - 1);
        int s = eidx[e], d = eidx[E + e];
        sidx[tid] = s; didx[tid] = d;
        dist_sh[tid] = dist[e];
        coordw_sh[tid] = 0.f;
        #pragma unroll
        for (int c = 0; c < 3; ++c) dir_sh[tid * 3 + c] = x[s * 3 + c] - x[d * 3 + c];
    }
    __syncthreads();

    // gather h[src] -> m[:,0:128], h[dst] -> m[:,128:256] (16B chunks, coalesced)
    for (int c = tid; c < 2048; c += 256) {
        int nr = c >> 4, piece = c & 15;
        int er = nr & 63;
        bool isd = nr >= 64;
        int node = isd ? didx[er] : sidx[er];
        uint4 v = ((const uint4*)(hb + (size_t)node * ND))[piece];
        *((uint4*)((char*)m_sh + er * (MP * 2) + (isd ? 256 : 0) + piece * 16)) = v;
    }
    // se = silu(dist*We1+be1) -> m[:,256:320]
    for (int i = tid; i < ET * ED; i += 256) {
        int er = i >> 6, j = i & 63;
        m_sh[er * MP + 2 * ND + j] = f2b(silu_f(fmaf(dist_sh[er], We1[j], be1[j])));
    }
    __syncthreads();

    // ---- GEMM1 pass A: coord hidden -> silu -> dot(Wc2) -> coordw ----
    {
        f32x4 acc[4][4];
        #pragma unroll
        for (int nti = 0; nti < 4; ++nti) {
            float b = bc1p[(wv * 4 + nti) * 16 + lc];
            #pragma unroll
            for (int rt = 0; rt < 4; ++rt) acc[rt][nti] = (f32x4){b, b, b, b};
        }
        for (int ks = 0; ks < 10; ++ks) {
            bf16x8 a[4];
            #pragma unroll
            for (int rt = 0; rt < 4; ++rt)
                a[rt] = *(const bf16x8*)&m_sh[(rt * 16 + lc) * MP + ks * 32 + q * 8];
            #pragma unroll
            for (int nti = 0; nti < 4; ++nti) {
                bf16x8 b = *(const bf16x8*)&Wc1s[((ks * 16 + wv * 4 + nti) * 64 + lane) * 8];
                #pragma unroll
                for (int rt = 0; rt < 4; ++rt)
                    acc[rt][nti] = __builtin_amdgcn_mfma_f32_16x16x32_bf16(a[rt], b, acc[rt][nti], 0, 0, 0);
            }
        }
        #pragma unroll
        for (int rt = 0; rt < 4; ++rt) {
            float p[4] = {0.f, 0.f, 0.f, 0.f};
            #pragma unroll
            for (int nti = 0; nti < 4; ++nti) {
                float wc = Wc2[(wv * 4 + nti) * 16 + lc];
                #pragma unroll
                for (int r = 0; r < 4; ++r) p[r] += silu_f(acc[rt][nti][r]) * wc;
            }
            #pragma unroll
            for (int r = 0; r < 4; ++r) {
                float v = p[r];
                v += __shfl_xor(v, 1); v += __shfl_xor(v, 2);
                v += __shfl_xor(v, 4); v += __shfl_xor(v, 8);
                if (lc == 0) atomicAdd(&coordw_sh[rt * 16 + q * 4 + r], v);
            }
        }
    }

    // ---- GEMM1 pass B: node hidden ----
    f32x4 accn[4][4];
    #pragma unroll
    for (int nti = 0; nti < 4; ++nti) {
        float b = bn1p[(wv * 4 + nti) * 16 + lc];
        #pragma unroll
        for (int rt = 0; rt < 4; ++rt) accn[rt][nti] = (f32x4){b, b, b, b};
    }
    for (int ks = 0; ks < 10; ++ks) {
        bf16x8 a[4];
        #pragma unroll
        for (int rt = 0; rt < 4; ++rt)
            a[rt] = *(const bf16x8*)&m_sh[(rt * 16 + lc) * MP + ks * 32 + q * 8];
        #pragma unroll
        for (int nti = 0; nti < 4; ++nti) {
            bf16x8 b = *(const bf16x8*)&Wn1s[((ks * 16 + wv * 4 + nti) * 64 + lane) * 8];
            #pragma unroll
            for (int rt = 0; rt < 4; ++rt)
                accn[rt][nti] = __builtin_amdgcn_mfma_f32_16x16x32_bf16(a[rt], b, accn[rt][nti], 0, 0, 0);
        }
    }
    __syncthreads();   // all waves done reading m_sh

    // hid = silu(accn) overlaid into m_sh storage, row-major [64][HP] bf16
    __hip_bfloat16* hid = m_sh;
    #pragma unroll
    for (int rt = 0; rt < 4; ++rt)
        #pragma unroll
        for (int nti = 0; nti < 4; ++nti)
            #pragma unroll
            for (int r = 0; r < 4; ++r)
                hid[(rt * 16 + q * 4 + r) * HP + (wv * 4 + nti) * 16 + lc] =
                    f2b(silu_f(accn[rt][nti][r]));
    __syncthreads();

    // ---- GEMM2: msg[64x128] = hid @ Wn2 + bn2 ----
    f32x4 acc2[4][2];
    #pragma unroll
    for (int nti = 0; nti < 2; ++nti) {
        float b = bn2[(wv * 2 + nti) * 16 + lc];
        #pragma unroll
        for (int rt = 0; rt < 4; ++rt) acc2[rt][nti] = (f32x4){b, b, b, b};
    }
    for (int ks = 0; ks < 8; ++ks) {
        bf16x8 a[4];
        #pragma unroll
        for (int rt = 0; rt < 4; ++rt)
            a[rt] = *(const bf16x8*)&hid[(rt * 16 + lc) * HP + ks * 32 + q * 8];
        #pragma unroll
        for (int nti = 0; nti < 2; ++nti) {
            bf16x8 b = *(const bf16x8*)&Wn2s[((ks * 8 + wv * 2 + nti) * 64 + lane) * 8];
            #pragma unroll
            for (int rt = 0; rt < 4; ++rt)
                acc2[rt][nti] = __builtin_amdgcn_mfma_f32_16x16x32_bf16(a[rt], b, acc2[rt][nti], 0, 0, 0);
        }
    }
    // scatter messages (16 consecutive f32 per quad -> coalesced atomics)
    #pragma unroll
    for (int rt = 0; rt < 4; ++rt)
        #pragma unroll
        for (int nti = 0; nti < 2; ++nti)
            #pragma unroll
            for (int r = 0; r < 4; ++r) {
                int er = rt * 16 + q * 4 + r;
                if (e0 + er < E)
                    atomicAdd(&h_agg[(size_t)didx[er] * ND + (wv * 2 + nti) * 16 + lc],
                              acc2[rt][nti][r]);
            }
    // scatter coord updates
    if (tid < ET && e0 + tid < E) {
        float w = coordw_sh[tid];
        int d = didx[tid];
        #pragma unroll
        for (int c = 0; c < 3; ++c)
            atomicAdd(&x_agg[d * 3 + c], w * dir_sh[tid * 3 + c]);
    }
}

__global__ __launch_bounds__(256) void egnn_finalize(
    const float* __restrict__ h, const float* __restrict__ x,
    const float* __restrict__ h_agg, const float* __restrict__ x_agg,
    float* __restrict__ out, int n_nodes)
{
    int i = blockIdx.x * 256 + threadIdx.x;
    int nh = n_nodes * ND;
    int total = nh + n_nodes * 3;
    if (i < nh)       out[i] = h[i] + h_agg[i];
    else if (i < total) { int k = i - nh; out[i] = x[k] + x_agg[k]; }
}

extern "C" void kernel_launch(void* const* d_in, const int* in_sizes, int n_in,
                              void* d_out, int out_size, void* d_ws, size_t ws_size,
                              hipStream_t stream)
{
    const float* h    = (const float*)d_in[0];
    const float* x    = (const float*)d_in[1];
    const int*   eidx = (const int*)d_in[2];
    const float* dist = (const float*)d_in[3];
    const float* Wn1  = (const float*)d_in[4];
    const float* bn1  = (const float*)d_in[5];
    const float* Wn2  = (const float*)d_in[6];
    const float* bn2  = (const float*)d_in[7];
    const float* Wc1  = (const float*)d_in[8];
    const float* bc1  = (const float*)d_in[9];
    const float* Wc2  = (const float*)d_in[10];
    const float* We1  = (const float*)d_in[11];
    const float* be1  = (const float*)d_in[12];
    const float* We2  = (const float*)d_in[13];
    // const float* be2 = d_in[14]  (folded into biases by prep_bias)

    const int E = in_sizes[3];
    const int N = in_sizes[0] / ND;

    // workspace layout
    float* h_agg = (float*)d_ws;                       // N*128 f32
    float* x_agg = h_agg + (size_t)N * ND;             // N*3
    float* bn1p  = x_agg + (size_t)N * 3;              // 256
    float* bc1p  = bn1p + HD;                          // 256
    __hip_bfloat16* hb   = (__hip_bfloat16*)(bc1p + HD);   // N*128 bf16
    __hip_bfloat16* Wn1s = hb + (size_t)N * ND;        // 81920
    __hip_bfloat16* Wc1s = Wn1s + 81920;               // 81920
    __hip_bfloat16* Wn2s = Wc1s + 81920;               // 32768

    hipMemsetAsync(d_ws, 0, ((size_t)N * ND + (size_t)N * 3) * sizeof(float), stream);

    int nh = N * ND;
    prep_h<<<(nh + 255) / 256, 256, 0, stream>>>(h, hb, nh);
    prep_w<<<768, 256, 0, stream>>>(Wn1, Wc1, Wn2, We2, Wn1s, Wc1s, Wn2s);
    prep_bias<<<2, 256, 0, stream>>>(bn1, bc1, Wn1, Wc1, (const float*)d_in[14], bn1p, bc1p);

    egnn_main<<<(E + ET - 1) / ET, 256, 0, stream>>>(
        hb, x, eidx, dist, Wn1s, Wc1s, Wn2s, bn1p, bc1p, bn2, Wc2,
        We1, be1, h_agg, x_agg, E);

    int total = N * ND + N * 3;
    egnn_finalize<<<(total + 255) / 256, 256, 0, stream>>>(
        h, x, h_agg, x_agg, (float*)d_out, N);
}

// Round 4
// 977.869 us; speedup vs baseline: 7.7426x; 1.0254x over previous
//
#include <hip/hip_runtime.h>
#include <hip/hip_bf16.h>

typedef __attribute__((ext_vector_type(8))) short bf16x8;
typedef __attribute__((ext_vector_type(4))) float f32x4;

constexpr int ND = 128;   // node dim
constexpr int HD = 256;   // hidden dim
constexpr int ED = 64;    // edge dim
constexpr int ET = 64;    // edges per block tile
constexpr int MP = 328;   // m_sh pitch in bf16 (656B, odd*16B -> bank stagger)
constexpr int HP = 264;   // hid pitch in bf16
constexpr int MSGP = 132; // msg pitch in f32

__device__ __forceinline__ float silu_f(float v) { return v / (1.0f + __expf(-v)); }
__device__ __forceinline__ __hip_bfloat16 f2b(float v) { return __float2bfloat16(v); }

// ---------- prep: h -> bf16 ----------
__global__ __launch_bounds__(256) void prep_h(const float* __restrict__ h,
                                              __hip_bfloat16* __restrict__ hb, int n) {
    int i = blockIdx.x * 256 + threadIdx.x;
    if (i < n) hb[i] = f2b(h[i]);
}

// ---------- prep: weights -> bf16, swizzled to B-fragment order ----------
__global__ __launch_bounds__(256) void prep_w(
    const float* __restrict__ Wn1, const float* __restrict__ Wc1,
    const float* __restrict__ Wn2, const float* __restrict__ We2,
    __hip_bfloat16* __restrict__ Wn1s, __hip_bfloat16* __restrict__ Wc1s,
    __hip_bfloat16* __restrict__ Wn2s)
{
    int id = blockIdx.x * 256 + threadIdx.x;
    if (id < 163840) {                      // Wn1s / Wc1s: 10 ks * 16 nt * 64 * 8
        int e = id;
        const float* W = Wn1; __hip_bfloat16* out = Wn1s;
        if (id >= 81920) { e -= 81920; W = Wc1; out = Wc1s; }
        int j = e & 7, lane = (e >> 3) & 63, nt = (e >> 9) & 15, ks = e >> 13;
        int k = ks * 32 + (lane >> 4) * 8 + j;
        int n = nt * 16 + (lane & 15);
        float v;
        if (k < 2 * ND) v = W[k * HD + n];
        else {
            int t = k - 2 * ND; v = 0.f;
            for (int u = 0; u < ED; ++u) v += We2[t * ED + u] * W[(2 * ND + u) * HD + n];
        }
        out[e] = f2b(v);
    } else if (id < 196608) {               // Wn2s: 8 ks * 8 nt * 64 * 8
        int e = id - 163840;
        int j = e & 7, lane = (e >> 3) & 63, nt = (e >> 9) & 7, ks = e >> 12;
        int k = ks * 32 + (lane >> 4) * 8 + j;
        int n = nt * 16 + (lane & 15);
        Wn2s[e] = f2b(Wn2[k * ND + n]);
    }
}

// ---------- prep: fold be2 @ W[256:320,:] into biases ----------
__global__ __launch_bounds__(256) void prep_bias(
    const float* __restrict__ bn1, const float* __restrict__ bc1,
    const float* __restrict__ Wn1, const float* __restrict__ Wc1,
    const float* __restrict__ be2,
    float* __restrict__ bn1p, float* __restrict__ bc1p)
{
    int n = blockIdx.x * 256 + threadIdx.x;
    if (n < HD) {
        float v = bn1[n];
        for (int t = 0; t < ED; ++t) v += be2[t] * Wn1[(2 * ND + t) * HD + n];
        bn1p[n] = v;
    } else if (n < 2 * HD) {
        int m = n - HD;
        float v = bc1[m];
        for (int t = 0; t < ED; ++t) v += be2[t] * Wc1[(2 * ND + t) * HD + m];
        bc1p[m] = v;
    }
}

// ---------- counting sort by dst ----------
__global__ __launch_bounds__(256) void s_hist(const int* __restrict__ eidx,
                                              int* __restrict__ cnt, int E) {
    int e = blockIdx.x * 256 + threadIdx.x;
    if (e < E) atomicAdd(&cnt[eidx[E + e]], 1);
}

__global__ __launch_bounds__(256) void s_scan1(const int* __restrict__ cnt,
                                               int* __restrict__ bsum, int N) {
    __shared__ int sh[256];
    int i = blockIdx.x * 256 + threadIdx.x;
    sh[threadIdx.x] = (i < N) ? cnt[i] : 0;
    __syncthreads();
    for (int s = 128; s > 0; s >>= 1) {
        if (threadIdx.x < s) sh[threadIdx.x] += sh[threadIdx.x + s];
        __syncthreads();
    }
    if (threadIdx.x == 0) bsum[blockIdx.x] = sh[0];
}

__global__ __launch_bounds__(256) void s_scan2(int* __restrict__ bsum, int nb) {
    __shared__ int sh[256];
    int t = threadIdx.x;
    int orig = (t < nb) ? bsum[t] : 0;
    sh[t] = orig;
    __syncthreads();
    for (int off = 1; off < 256; off <<= 1) {
        int u = (t >= off) ? sh[t - off] : 0;
        __syncthreads();
        sh[t] += u;
        __syncthreads();
    }
    if (t < nb) bsum[t] = sh[t] - orig;   // exclusive
}

__global__ __launch_bounds__(256) void s_scan3(const int* __restrict__ cnt,
                                               const int* __restrict__ bsum,
                                               int* __restrict__ head, int N) {
    __shared__ int sh[256];
    int t = threadIdx.x, i = blockIdx.x * 256 + t;
    int v = (i < N) ? cnt[i] : 0;
    sh[t] = v;
    __syncthreads();
    for (int off = 1; off < 256; off <<= 1) {
        int u = (t >= off) ? sh[t - off] : 0;
        __syncthreads();
        sh[t] += u;
        __syncthreads();
    }
    if (i < N) head[i] = bsum[blockIdx.x] + sh[t] - v;  // exclusive prefix
}

__global__ __launch_bounds__(256) void s_scatter(
    const int* __restrict__ eidx, const float* __restrict__ dist,
    int* __restrict__ head, int* __restrict__ ssrc, int* __restrict__ sdst,
    float* __restrict__ sdist, int E)
{
    int e = blockIdx.x * 256 + threadIdx.x;
    if (e < E) {
        int d = eidx[E + e];
        int pos = atomicAdd(&head[d], 1);
        ssrc[pos] = eidx[e];
        sdst[pos] = d;
        sdist[pos] = dist[e];
    }
}

// ---------- main fused edge kernel (edges sorted by dst) ----------
__global__ __launch_bounds__(256, 3) void egnn_main(
    const __hip_bfloat16* __restrict__ hb,
    const float* __restrict__ x,
    const int* __restrict__ ssrc, const int* __restrict__ sdst,
    const float* __restrict__ sdist,
    const __hip_bfloat16* __restrict__ Wn1s,
    const __hip_bfloat16* __restrict__ Wc1s,
    const __hip_bfloat16* __restrict__ Wn2s,
    const float* __restrict__ bn1p, const float* __restrict__ bc1p,
    const float* __restrict__ bn2,  const float* __restrict__ Wc2,
    const float* __restrict__ We1,  const float* __restrict__ be1,
    float* __restrict__ h_agg, float* __restrict__ x_agg,
    int E)
{
    __shared__ __align__(16) __hip_bfloat16 m_sh[ET * MP];  // 41984 B; overlaid by hid, then msg
    __shared__ float dir_sh[ET * 3];
    __shared__ float coordw_sh[ET];
    __shared__ float dist_sh[ET];
    __shared__ int   sidx[ET], didx[ET];

    const int tid  = threadIdx.x;
    const int lane = tid & 63;
    const int wv   = tid >> 6;
    const int q    = lane >> 4;
    const int lc   = lane & 15;
    const int e0   = blockIdx.x * ET;

    if (tid < ET) {
        int e = min(e0 + tid, E - 1);
        int s = ssrc[e], d = sdst[e];
        sidx[tid] = s; didx[tid] = d;
        dist_sh[tid] = sdist[e];
        coordw_sh[tid] = 0.f;
        #pragma unroll
        for (int c = 0; c < 3; ++c) dir_sh[tid * 3 + c] = x[s * 3 + c] - x[d * 3 + c];
    }
    __syncthreads();

    // gather h[src] -> m[:,0:128], h[dst] -> m[:,128:256]
    for (int c = tid; c < 2048; c += 256) {
        int nr = c >> 4, piece = c & 15;
        int er = nr & 63;
        bool isd = nr >= 64;
        int node = isd ? didx[er] : sidx[er];
        uint4 v = ((const uint4*)(hb + (size_t)node * ND))[piece];
        *((uint4*)((char*)m_sh + er * (MP * 2) + (isd ? 256 : 0) + piece * 16)) = v;
    }
    // se = silu(dist*We1+be1) -> m[:,256:320]
    for (int i = tid; i < ET * ED; i += 256) {
        int er = i >> 6, j = i & 63;
        m_sh[er * MP + 2 * ND + j] = f2b(silu_f(fmaf(dist_sh[er], We1[j], be1[j])));
    }
    __syncthreads();

    // ---- GEMM1 pass A: coord hidden -> silu -> dot(Wc2) -> coordw ----
    {
        f32x4 acc[4][4];
        #pragma unroll
        for (int nti = 0; nti < 4; ++nti) {
            float b = bc1p[(wv * 4 + nti) * 16 + lc];
            #pragma unroll
            for (int rt = 0; rt < 4; ++rt) acc[rt][nti] = (f32x4){b, b, b, b};
        }
        for (int ks = 0; ks < 10; ++ks) {
            bf16x8 a[4];
            #pragma unroll
            for (int rt = 0; rt < 4; ++rt)
                a[rt] = *(const bf16x8*)&m_sh[(rt * 16 + lc) * MP + ks * 32 + q * 8];
            #pragma unroll
            for (int nti = 0; nti < 4; ++nti) {
                bf16x8 b = *(const bf16x8*)&Wc1s[((ks * 16 + wv * 4 + nti) * 64 + lane) * 8];
                #pragma unroll
                for (int rt = 0; rt < 4; ++rt)
                    acc[rt][nti] = __builtin_amdgcn_mfma_f32_16x16x32_bf16(a[rt], b, acc[rt][nti], 0, 0, 0);
            }
        }
        #pragma unroll
        for (int rt = 0; rt < 4; ++rt) {
            float p[4] = {0.f, 0.f, 0.f, 0.f};
            #pragma unroll
            for (int nti = 0; nti < 4; ++nti) {
                float wc = Wc2[(wv * 4 + nti) * 16 + lc];
                #pragma unroll
                for (int r = 0; r < 4; ++r) p[r] += silu_f(acc[rt][nti][r]) * wc;
            }
            #pragma unroll
            for (int r = 0; r < 4; ++r) {
                float v = p[r];
                v += __shfl_xor(v, 1); v += __shfl_xor(v, 2);
                v += __shfl_xor(v, 4); v += __shfl_xor(v, 8);
                if (lc == 0) atomicAdd(&coordw_sh[rt * 16 + q * 4 + r], v);
            }
        }
    }

    // ---- GEMM1 pass B: node hidden ----
    f32x4 accn[4][4];
    #pragma unroll
    for (int nti = 0; nti < 4; ++nti) {
        float b = bn1p[(wv * 4 + nti) * 16 + lc];
        #pragma unroll
        for (int rt = 0; rt < 4; ++rt) accn[rt][nti] = (f32x4){b, b, b, b};
    }
    for (int ks = 0; ks < 10; ++ks) {
        bf16x8 a[4];
        #pragma unroll
        for (int rt = 0; rt < 4; ++rt)
            a[rt] = *(const bf16x8*)&m_sh[(rt * 16 + lc) * MP + ks * 32 + q * 8];
        #pragma unroll
        for (int nti = 0; nti < 4; ++nti) {
            bf16x8 b = *(const bf16x8*)&Wn1s[((ks * 16 + wv * 4 + nti) * 64 + lane) * 8];
            #pragma unroll
            for (int rt = 0; rt < 4; ++rt)
                accn[rt][nti] = __builtin_amdgcn_mfma_f32_16x16x32_bf16(a[rt], b, accn[rt][nti], 0, 0, 0);
        }
    }
    __syncthreads();   // all waves done reading m_sh

    // hid = silu(accn) overlaid into m_sh storage, [64][HP] bf16
    __hip_bfloat16* hid = m_sh;
    #pragma unroll
    for (int rt = 0; rt < 4; ++rt)
        #pragma unroll
        for (int nti = 0; nti < 4; ++nti)
            #pragma unroll
            for (int r = 0; r < 4; ++r)
                hid[(rt * 16 + q * 4 + r) * HP + (wv * 4 + nti) * 16 + lc] =
                    f2b(silu_f(accn[rt][nti][r]));
    __syncthreads();

    // ---- GEMM2: msg[64x128] = hid @ Wn2 + bn2 ----
    f32x4 acc2[4][2];
    #pragma unroll
    for (int nti = 0; nti < 2; ++nti) {
        float b = bn2[(wv * 2 + nti) * 16 + lc];
        #pragma unroll
        for (int rt = 0; rt < 4; ++rt) acc2[rt][nti] = (f32x4){b, b, b, b};
    }
    for (int ks = 0; ks < 8; ++ks) {
        bf16x8 a[4];
        #pragma unroll
        for (int rt = 0; rt < 4; ++rt)
            a[rt] = *(const bf16x8*)&hid[(rt * 16 + lc) * HP + ks * 32 + q * 8];
        #pragma unroll
        for (int nti = 0; nti < 2; ++nti) {
            bf16x8 b = *(const bf16x8*)&Wn2s[((ks * 8 + wv * 2 + nti) * 64 + lane) * 8];
            #pragma unroll
            for (int rt = 0; rt < 4; ++rt)
                acc2[rt][nti] = __builtin_amdgcn_mfma_f32_16x16x32_bf16(a[rt], b, acc2[rt][nti], 0, 0, 0);
        }
    }
    __syncthreads();   // waves done reading hid; safe to overlay msg

    // write messages to LDS [64][MSGP] f32 (33792 B, fits in m_sh region)
    float* msg = (float*)m_sh;
    #pragma unroll
    for (int rt = 0; rt < 4; ++rt)
        #pragma unroll
        for (int nti = 0; nti < 2; ++nti)
            #pragma unroll
            for (int r = 0; r < 4; ++r)
                msg[(rt * 16 + q * 4 + r) * MSGP + (wv * 2 + nti) * 16 + lc] = acc2[rt][nti][r];
    __syncthreads();

    // ---- segmented flush: edges sorted by dst -> one atomic per (segment, col) ----
    {
        int c  = tid & 127;
        int r0 = (tid >> 7) * 32;
        float run = 0.f; int cur = -1;
        for (int r = r0; r < r0 + 32; ++r) {
            int d = (e0 + r < E) ? didx[r] : -1;
            if (d != cur) {
                if (cur >= 0) atomicAdd(&h_agg[(size_t)cur * ND + c], run);
                run = 0.f; cur = d;
            }
            if (d >= 0) run += msg[r * MSGP + c];
        }
        if (cur >= 0) atomicAdd(&h_agg[(size_t)cur * ND + c], run);
    }
    // coord updates, same segmented reduction (3 cols x 2 halves)
    if (tid < 6) {
        int c = tid % 3, r0 = (tid / 3) * 32;
        float run = 0.f; int cur = -1;
        for (int r = r0; r < r0 + 32; ++r) {
            int d = (e0 + r < E) ? didx[r] : -1;
            if (d != cur) {
                if (cur >= 0) atomicAdd(&x_agg[cur * 3 + c], run);
                run = 0.f; cur = d;
            }
            if (d >= 0) run += coordw_sh[r] * dir_sh[r * 3 + c];
        }
        if (cur >= 0) atomicAdd(&x_agg[cur * 3 + c], run);
    }
}

__global__ __launch_bounds__(256) void egnn_finalize(
    const float* __restrict__ h, const float* __restrict__ x,
    const float* __restrict__ h_agg, const float* __restrict__ x_agg,
    float* __restrict__ out, int n_nodes)
{
    int i = blockIdx.x * 256 + threadIdx.x;
    int nh = n_nodes * ND;
    int total = nh + n_nodes * 3;
    if (i < nh)       out[i] = h[i] + h_agg[i];
    else if (i < total) { int k = i - nh; out[i] = x[k] + x_agg[k]; }
}

extern "C" void kernel_launch(void* const* d_in, const int* in_sizes, int n_in,
                              void* d_out, int out_size, void* d_ws, size_t ws_size,
                              hipStream_t stream)
{
    const float* h    = (const float*)d_in[0];
    const float* x    = (const float*)d_in[1];
    const int*   eidx = (const int*)d_in[2];
    const float* dist = (const float*)d_in[3];
    const float* Wn1  = (const float*)d_in[4];
    const float* bn1  = (const float*)d_in[5];
    const float* Wn2  = (const float*)d_in[6];
    const float* bn2  = (const float*)d_in[7];
    const float* Wc1  = (const float*)d_in[8];
    const float* bc1  = (const float*)d_in[9];
    const float* Wc2  = (const float*)d_in[10];
    const float* We1  = (const float*)d_in[11];
    const float* be1  = (const float*)d_in[12];
    const float* We2  = (const float*)d_in[13];

    const int E = in_sizes[3];
    const int N = in_sizes[0] / ND;

    // workspace layout (all segments 16B-aligned)
    float* h_agg = (float*)d_ws;                           // N*ND
    float* x_agg = h_agg + (size_t)N * ND;                 // N*3
    float* bn1p  = x_agg + (size_t)N * 3;                  // HD
    float* bc1p  = bn1p + HD;                              // HD
    __hip_bfloat16* hb   = (__hip_bfloat16*)(bc1p + HD);   // N*ND bf16
    __hip_bfloat16* Wn1s = hb + (size_t)N * ND;            // 81920
    __hip_bfloat16* Wc1s = Wn1s + 81920;                   // 81920
    __hip_bfloat16* Wn2s = Wc1s + 81920;                   // 32768
    int*   cnt   = (int*)(Wn2s + 32768);                   // N
    int*   bsum  = cnt + N;                                // 256
    int*   head  = bsum + 256;                             // N
    int*   ssrc  = head + N;                               // E
    int*   sdst  = ssrc + E;                               // E
    float* sdist = (float*)(sdst + E);                     // E

    hipMemsetAsync(d_ws, 0, ((size_t)N * ND + (size_t)N * 3) * sizeof(float), stream);
    hipMemsetAsync(cnt, 0, (size_t)N * sizeof(int), stream);

    const int nbN = (N + 255) / 256;
    const int nbE = (E + 255) / 256;

    s_hist   <<<nbE, 256, 0, stream>>>(eidx, cnt, E);
    s_scan1  <<<nbN, 256, 0, stream>>>(cnt, bsum, N);
    s_scan2  <<<1,   256, 0, stream>>>(bsum, nbN);
    s_scan3  <<<nbN, 256, 0, stream>>>(cnt, bsum, head, N);
    s_scatter<<<nbE, 256, 0, stream>>>(eidx, dist, head, ssrc, sdst, sdist, E);

    int nh = N * ND;
    prep_h<<<(nh + 255) / 256, 256, 0, stream>>>(h, hb, nh);
    prep_w<<<768, 256, 0, stream>>>(Wn1, Wc1, Wn2, We2, Wn1s, Wc1s, Wn2s);
    prep_bias<<<2, 256, 0, stream>>>(bn1, bc1, Wn1, Wc1, (const float*)d_in[14], bn1p, bc1p);

    egnn_main<<<(E + ET - 1) / ET, 256, 0, stream>>>(
        hb, x, ssrc, sdst, sdist, Wn1s, Wc1s, Wn2s, bn1p, bc1p, bn2, Wc2,
        We1, be1, h_agg, x_agg, E);

    int total = N * ND + N * 3;
    egnn_finalize<<<(total + 255) / 256, 256, 0, stream>>>(
        h, x, h_agg, x_agg, (float*)d_out, N);
}

// Round 5
// 897.741 us; speedup vs baseline: 8.4337x; 1.0893x over previous
//
#include <hip/hip_runtime.h>
#include <hip/hip_bf16.h>

typedef __attribute__((ext_vector_type(8))) short bf16x8;
typedef __attribute__((ext_vector_type(4))) float f32x4;

constexpr int ND = 128;   // node dim
constexpr int HD = 256;   // hidden dim
constexpr int ED = 64;    // edge dim
constexpr int ET = 64;    // edges per block tile
constexpr int MPn = 200;  // m pitch bf16 (400B, odd*16B -> 2-way-free banks)
constexpr int HP  = 264;  // hid pitch bf16 (528B)
constexpr int MSGP = 132; // msg pitch f32 (528B)
constexpr int QC  = 512;  // Q cols: [node 256 | coord 256]

__device__ __forceinline__ float silu_f(float v) { return v / (1.0f + __expf(-v)); }
__device__ __forceinline__ __hip_bfloat16 f2b(float v) { return __float2bfloat16(v); }

// ---------- prep: h -> bf16 ----------
__global__ __launch_bounds__(256) void prep_h(const float* __restrict__ h,
                                              __hip_bfloat16* __restrict__ hb, int n) {
    int i = blockIdx.x * 256 + threadIdx.x;
    if (i < n) hb[i] = f2b(h[i]);
}

// ---------- prep: weights -> bf16, swizzled to B-fragment order ----------
// Swizzled element ((ks*16+nt)*64+lane)*8+j = W'[ks*32+(lane>>4)*8+j][nt*16+(lane&15)]
// where W' is the 320-row folded matrix (rows 256:320 = We2 @ W[256:320,:]).
__global__ __launch_bounds__(256) void prep_w(
    const float* __restrict__ Wn1, const float* __restrict__ Wc1,
    const float* __restrict__ Wn2, const float* __restrict__ We2,
    __hip_bfloat16* __restrict__ Wn1s, __hip_bfloat16* __restrict__ Wc1s,
    __hip_bfloat16* __restrict__ Wn2s)
{
    int id = blockIdx.x * 256 + threadIdx.x;
    if (id < 163840) {                      // Wn1s / Wc1s: 10 ks * 16 nt * 64 * 8
        int e = id;
        const float* W = Wn1; __hip_bfloat16* out = Wn1s;
        if (id >= 81920) { e -= 81920; W = Wc1; out = Wc1s; }
        int j = e & 7, lane = (e >> 3) & 63, nt = (e >> 9) & 15, ks = e >> 13;
        int k = ks * 32 + (lane >> 4) * 8 + j;
        int n = nt * 16 + (lane & 15);
        float v;
        if (k < 2 * ND) v = W[k * HD + n];
        else {
            int t = k - 2 * ND; v = 0.f;
            for (int u = 0; u < ED; ++u) v += We2[t * ED + u] * W[(2 * ND + u) * HD + n];
        }
        out[e] = f2b(v);
    } else if (id < 196608) {               // Wn2s: 8 ks * 8 nt * 64 * 8
        int e = id - 163840;
        int j = e & 7, lane = (e >> 3) & 63, nt = (e >> 9) & 7, ks = e >> 12;
        int k = ks * 32 + (lane >> 4) * 8 + j;
        int n = nt * 16 + (lane & 15);
        Wn2s[e] = f2b(Wn2[k * ND + n]);
    }
}

// ---------- prep: fold be2 @ W[256:320,:] into biases ----------
__global__ __launch_bounds__(256) void prep_bias(
    const float* __restrict__ bn1, const float* __restrict__ bc1,
    const float* __restrict__ Wn1, const float* __restrict__ Wc1,
    const float* __restrict__ be2,
    float* __restrict__ bn1p, float* __restrict__ bc1p)
{
    int n = blockIdx.x * 256 + threadIdx.x;
    if (n < HD) {
        float v = bn1[n];
        for (int t = 0; t < ED; ++t) v += be2[t] * Wn1[(2 * ND + t) * HD + n];
        bn1p[n] = v;
    } else if (n < 2 * HD) {
        int m = n - HD;
        float v = bc1[m];
        for (int t = 0; t < ED; ++t) v += be2[t] * Wc1[(2 * ND + t) * HD + m];
        bc1p[m] = v;
    }
}

// ---------- prep: Q = h @ [Wn1_mid | Wc1_mid]  (K-rows 128:256 -> ks 4..7) ----------
// grid.x = row tiles, grid.y = 0 (node cols, Wn1s) / 1 (coord cols, Wc1s)
__global__ __launch_bounds__(256) void prep_q(
    const __hip_bfloat16* __restrict__ hb,
    const __hip_bfloat16* __restrict__ Wn1s,
    const __hip_bfloat16* __restrict__ Wc1s,
    __hip_bfloat16* __restrict__ Q, int N)
{
    __shared__ __align__(16) __hip_bfloat16 a_sh[64 * 136];  // pitch 272B
    const int tid = threadIdx.x;
    const int lane = tid & 63, wv = tid >> 6;
    const int q = lane >> 4, lc = lane & 15;
    const int row0 = blockIdx.x * 64;
    const __hip_bfloat16* Ws = blockIdx.y ? Wc1s : Wn1s;
    const int colbase = blockIdx.y * 256;

    // stage 64 rows of hb (128 bf16 each)
    for (int i = tid; i < 64 * 16; i += 256) {
        int r = i >> 4, piece = i & 15;
        int node = min(row0 + r, N - 1);
        uint4 v = ((const uint4*)(hb + (size_t)node * ND))[piece];
        *((uint4*)((char*)a_sh + r * 272 + piece * 16)) = v;
    }
    __syncthreads();

    f32x4 acc[4][4];
    #pragma unroll
    for (int rt = 0; rt < 4; ++rt)
        #pragma unroll
        for (int nti = 0; nti < 4; ++nti) acc[rt][nti] = (f32x4){0.f, 0.f, 0.f, 0.f};

    for (int ks = 0; ks < 4; ++ks) {
        bf16x8 a[4];
        #pragma unroll
        for (int rt = 0; rt < 4; ++rt)
            a[rt] = *(const bf16x8*)&a_sh[(rt * 16 + lc) * 136 + ks * 32 + q * 8];
        #pragma unroll
        for (int nti = 0; nti < 4; ++nti) {
            bf16x8 b = *(const bf16x8*)&Ws[(((ks + 4) * 16 + wv * 4 + nti) * 64 + lane) * 8];
            #pragma unroll
            for (int rt = 0; rt < 4; ++rt)
                acc[rt][nti] = __builtin_amdgcn_mfma_f32_16x16x32_bf16(a[rt], b, acc[rt][nti], 0, 0, 0);
        }
    }
    #pragma unroll
    for (int rt = 0; rt < 4; ++rt)
        #pragma unroll
        for (int nti = 0; nti < 4; ++nti)
            #pragma unroll
            for (int r = 0; r < 4; ++r) {
                int node = row0 + rt * 16 + q * 4 + r;
                if (node < N)
                    Q[(size_t)node * QC + colbase + (wv * 4 + nti) * 16 + lc] =
                        f2b(acc[rt][nti][r]);
            }
}

// ---------- counting sort by dst ----------
__global__ __launch_bounds__(256) void s_hist(const int* __restrict__ eidx,
                                              int* __restrict__ cnt, int E) {
    int e = blockIdx.x * 256 + threadIdx.x;
    if (e < E) atomicAdd(&cnt[eidx[E + e]], 1);
}

__global__ __launch_bounds__(256) void s_scan1(const int* __restrict__ cnt,
                                               int* __restrict__ bsum, int N) {
    __shared__ int sh[256];
    int i = blockIdx.x * 256 + threadIdx.x;
    sh[threadIdx.x] = (i < N) ? cnt[i] : 0;
    __syncthreads();
    for (int s = 128; s > 0; s >>= 1) {
        if (threadIdx.x < s) sh[threadIdx.x] += sh[threadIdx.x + s];
        __syncthreads();
    }
    if (threadIdx.x == 0) bsum[blockIdx.x] = sh[0];
}

__global__ __launch_bounds__(256) void s_scan2(int* __restrict__ bsum, int nb) {
    __shared__ int sh[256];
    int t = threadIdx.x;
    int orig = (t < nb) ? bsum[t] : 0;
    sh[t] = orig;
    __syncthreads();
    for (int off = 1; off < 256; off <<= 1) {
        int u = (t >= off) ? sh[t - off] : 0;
        __syncthreads();
        sh[t] += u;
        __syncthreads();
    }
    if (t < nb) bsum[t] = sh[t] - orig;   // exclusive
}

__global__ __launch_bounds__(256) void s_scan3(const int* __restrict__ cnt,
                                               const int* __restrict__ bsum,
                                               int* __restrict__ head, int N) {
    __shared__ int sh[256];
    int t = threadIdx.x, i = blockIdx.x * 256 + t;
    int v = (i < N) ? cnt[i] : 0;
    sh[t] = v;
    __syncthreads();
    for (int off = 1; off < 256; off <<= 1) {
        int u = (t >= off) ? sh[t - off] : 0;
        __syncthreads();
        sh[t] += u;
        __syncthreads();
    }
    if (i < N) head[i] = bsum[blockIdx.x] + sh[t] - v;  // exclusive prefix
}

__global__ __launch_bounds__(256) void s_scatter(
    const int* __restrict__ eidx, const float* __restrict__ dist,
    int* __restrict__ head, int* __restrict__ ssrc, int* __restrict__ sdst,
    float* __restrict__ sdist, int E)
{
    int e = blockIdx.x * 256 + threadIdx.x;
    if (e < E) {
        int d = eidx[E + e];
        int pos = atomicAdd(&head[d], 1);
        ssrc[pos] = eidx[e];
        sdst[pos] = d;
        sdist[pos] = dist[e];
    }
}

// ---------- main fused edge kernel (edges sorted by dst; dst factored via Q) ----------
__global__ __launch_bounds__(256, 4) void egnn_main(
    const __hip_bfloat16* __restrict__ hb,
    const float* __restrict__ x,
    const int* __restrict__ ssrc, const int* __restrict__ sdst,
    const float* __restrict__ sdist,
    const __hip_bfloat16* __restrict__ Wn1s,
    const __hip_bfloat16* __restrict__ Wc1s,
    const __hip_bfloat16* __restrict__ Wn2s,
    const __hip_bfloat16* __restrict__ Q,
    const float* __restrict__ bn1p, const float* __restrict__ bc1p,
    const float* __restrict__ bn2,  const float* __restrict__ Wc2,
    const float* __restrict__ We1,  const float* __restrict__ be1,
    float* __restrict__ h_agg, float* __restrict__ x_agg,
    int E)
{
    // overlay: m [64][MPn] bf16 (25.6KB) -> hid [64][HP] bf16 (33.8KB) -> msg [64][MSGP] f32 (33.8KB)
    __shared__ __align__(16) unsigned char smem[ET * HP * 2];
    __shared__ float dir_sh[ET * 3];
    __shared__ float coordw_sh[ET];
    __shared__ float dist_sh[ET];
    __shared__ int   sidx[ET], didx[ET];

    __hip_bfloat16* m_sh = (__hip_bfloat16*)smem;

    const int tid  = threadIdx.x;
    const int lane = tid & 63;
    const int wv   = tid >> 6;
    const int q    = lane >> 4;
    const int lc   = lane & 15;
    const int e0   = blockIdx.x * ET;

    if (tid < ET) {
        int e = min(e0 + tid, E - 1);
        int s = ssrc[e], d = sdst[e];
        sidx[tid] = s; didx[tid] = d;
        dist_sh[tid] = sdist[e];
        coordw_sh[tid] = 0.f;
        #pragma unroll
        for (int c = 0; c < 3; ++c) dir_sh[tid * 3 + c] = x[s * 3 + c] - x[d * 3 + c];
    }
    __syncthreads();

    // gather h[src] -> m[:,0:128]
    for (int i = tid; i < ET * 16; i += 256) {
        int er = i >> 4, piece = i & 15;
        uint4 v = ((const uint4*)(hb + (size_t)sidx[er] * ND))[piece];
        *((uint4*)((char*)m_sh + er * (MPn * 2) + piece * 16)) = v;
    }
    // se = silu(dist*We1+be1) -> m[:,128:192]
    for (int i = tid; i < ET * ED; i += 256) {
        int er = i >> 6, j = i & 63;
        m_sh[er * MPn + ND + j] = f2b(silu_f(fmaf(dist_sh[er], We1[j], be1[j])));
    }
    __syncthreads();

    // ---- GEMM1 pass A: coord hidden = [h_src|se]@Wc' + Q[dst][256:512] + bias ----
    {
        f32x4 acc[4][4];
        #pragma unroll
        for (int nti = 0; nti < 4; ++nti) {
            float b = bc1p[(wv * 4 + nti) * 16 + lc];
            #pragma unroll
            for (int rt = 0; rt < 4; ++rt) acc[rt][nti] = (f32x4){b, b, b, b};
        }
        for (int ks = 0; ks < 6; ++ks) {
            int bk = (ks < 4) ? ks : ks + 4;   // ks 4,5 -> folded se rows (orig ks 8,9)
            bf16x8 a[4];
            #pragma unroll
            for (int rt = 0; rt < 4; ++rt)
                a[rt] = *(const bf16x8*)&m_sh[(rt * 16 + lc) * MPn + ks * 32 + q * 8];
            #pragma unroll
            for (int nti = 0; nti < 4; ++nti) {
                bf16x8 b = *(const bf16x8*)&Wc1s[((bk * 16 + wv * 4 + nti) * 64 + lane) * 8];
                #pragma unroll
                for (int rt = 0; rt < 4; ++rt)
                    acc[rt][nti] = __builtin_amdgcn_mfma_f32_16x16x32_bf16(a[rt], b, acc[rt][nti], 0, 0, 0);
            }
        }
        #pragma unroll
        for (int rt = 0; rt < 4; ++rt) {
            int dd[4];
            #pragma unroll
            for (int r = 0; r < 4; ++r) dd[r] = didx[rt * 16 + q * 4 + r];
            float p[4] = {0.f, 0.f, 0.f, 0.f};
            #pragma unroll
            for (int nti = 0; nti < 4; ++nti) {
                int c = 256 + (wv * 4 + nti) * 16 + lc;
                float wc = Wc2[(wv * 4 + nti) * 16 + lc];
                #pragma unroll
                for (int r = 0; r < 4; ++r) {
                    float v = acc[rt][nti][r] + __bfloat162float(Q[(size_t)dd[r] * QC + c]);
                    p[r] += silu_f(v) * wc;
                }
            }
            #pragma unroll
            for (int r = 0; r < 4; ++r) {
                float v = p[r];
                v += __shfl_xor(v, 1); v += __shfl_xor(v, 2);
                v += __shfl_xor(v, 4); v += __shfl_xor(v, 8);
                if (lc == 0) atomicAdd(&coordw_sh[rt * 16 + q * 4 + r], v);
            }
        }
    }

    // ---- GEMM1 pass B: node hidden ----
    f32x4 accn[4][4];
    #pragma unroll
    for (int nti = 0; nti < 4; ++nti) {
        float b = bn1p[(wv * 4 + nti) * 16 + lc];
        #pragma unroll
        for (int rt = 0; rt < 4; ++rt) accn[rt][nti] = (f32x4){b, b, b, b};
    }
    for (int ks = 0; ks < 6; ++ks) {
        int bk = (ks < 4) ? ks : ks + 4;
        bf16x8 a[4];
        #pragma unroll
        for (int rt = 0; rt < 4; ++rt)
            a[rt] = *(const bf16x8*)&m_sh[(rt * 16 + lc) * MPn + ks * 32 + q * 8];
        #pragma unroll
        for (int nti = 0; nti < 4; ++nti) {
            bf16x8 b = *(const bf16x8*)&Wn1s[((bk * 16 + wv * 4 + nti) * 64 + lane) * 8];
            #pragma unroll
            for (int rt = 0; rt < 4; ++rt)
                accn[rt][nti] = __builtin_amdgcn_mfma_f32_16x16x32_bf16(a[rt], b, accn[rt][nti], 0, 0, 0);
        }
    }
    __syncthreads();   // all waves done reading m_sh

    // hid = silu(accn + Q[dst][node cols]) overlaid into smem, [64][HP] bf16
    __hip_bfloat16* hid = (__hip_bfloat16*)smem;
    #pragma unroll
    for (int rt = 0; rt < 4; ++rt) {
        int dd[4];
        #pragma unroll
        for (int r = 0; r < 4; ++r) dd[r] = didx[rt * 16 + q * 4 + r];
        #pragma unroll
        for (int nti = 0; nti < 4; ++nti) {
            int c = (wv * 4 + nti) * 16 + lc;
            #pragma unroll
            for (int r = 0; r < 4; ++r) {
                float v = accn[rt][nti][r] + __bfloat162float(Q[(size_t)dd[r] * QC + c]);
                hid[(rt * 16 + q * 4 + r) * HP + c] = f2b(silu_f(v));
            }
        }
    }
    __syncthreads();

    // ---- GEMM2: msg[64x128] = hid @ Wn2 + bn2 ----
    f32x4 acc2[4][2];
    #pragma unroll
    for (int nti = 0; nti < 2; ++nti) {
        float b = bn2[(wv * 2 + nti) * 16 + lc];
        #pragma unroll
        for (int rt = 0; rt < 4; ++rt) acc2[rt][nti] = (f32x4){b, b, b, b};
    }
    for (int ks = 0; ks < 8; ++ks) {
        bf16x8 a[4];
        #pragma unroll
        for (int rt = 0; rt < 4; ++rt)
            a[rt] = *(const bf16x8*)&hid[(rt * 16 + lc) * HP + ks * 32 + q * 8];
        #pragma unroll
        for (int nti = 0; nti < 2; ++nti) {
            bf16x8 b = *(const bf16x8*)&Wn2s[((ks * 8 + wv * 2 + nti) * 64 + lane) * 8];
            #pragma unroll
            for (int rt = 0; rt < 4; ++rt)
                acc2[rt][nti] = __builtin_amdgcn_mfma_f32_16x16x32_bf16(a[rt], b, acc2[rt][nti], 0, 0, 0);
        }
    }
    __syncthreads();   // waves done reading hid; safe to overlay msg

    float* msg = (float*)smem;
    #pragma unroll
    for (int rt = 0; rt < 4; ++rt)
        #pragma unroll
        for (int nti = 0; nti < 2; ++nti)
            #pragma unroll
            for (int r = 0; r < 4; ++r)
                msg[(rt * 16 + q * 4 + r) * MSGP + (wv * 2 + nti) * 16 + lc] = acc2[rt][nti][r];
    __syncthreads();

    // ---- segmented flush: one atomic per (segment, col) ----
    {
        int c  = tid & 127;
        int r0 = (tid >> 7) * 32;
        float run = 0.f; int cur = -1;
        for (int r = r0; r < r0 + 32; ++r) {
            int d = (e0 + r < E) ? didx[r] : -1;
            if (d != cur) {
                if (cur >= 0) atomicAdd(&h_agg[(size_t)cur * ND + c], run);
                run = 0.f; cur = d;
            }
            if (d >= 0) run += msg[r * MSGP + c];
        }
        if (cur >= 0) atomicAdd(&h_agg[(size_t)cur * ND + c], run);
    }
    if (tid < 6) {
        int c = tid % 3, r0 = (tid / 3) * 32;
        float run = 0.f; int cur = -1;
        for (int r = r0; r < r0 + 32; ++r) {
            int d = (e0 + r < E) ? didx[r] : -1;
            if (d != cur) {
                if (cur >= 0) atomicAdd(&x_agg[cur * 3 + c], run);
                run = 0.f; cur = d;
            }
            if (d >= 0) run += coordw_sh[r] * dir_sh[r * 3 + c];
        }
        if (cur >= 0) atomicAdd(&x_agg[cur * 3 + c], run);
    }
}

__global__ __launch_bounds__(256) void egnn_finalize(
    const float* __restrict__ h, const float* __restrict__ x,
    const float* __restrict__ h_agg, const float* __restrict__ x_agg,
    float* __restrict__ out, int n_nodes)
{
    int i = blockIdx.x * 256 + threadIdx.x;
    int nh = n_nodes * ND;
    int total = nh + n_nodes * 3;
    if (i < nh)       out[i] = h[i] + h_agg[i];
    else if (i < total) { int k = i - nh; out[i] = x[k] + x_agg[k]; }
}

extern "C" void kernel_launch(void* const* d_in, const int* in_sizes, int n_in,
                              void* d_out, int out_size, void* d_ws, size_t ws_size,
                              hipStream_t stream)
{
    const float* h    = (const float*)d_in[0];
    const float* x    = (const float*)d_in[1];
    const int*   eidx = (const int*)d_in[2];
    const float* dist = (const float*)d_in[3];
    const float* Wn1  = (const float*)d_in[4];
    const float* bn1  = (const float*)d_in[5];
    const float* Wn2  = (const float*)d_in[6];
    const float* bn2  = (const float*)d_in[7];
    const float* Wc1  = (const float*)d_in[8];
    const float* bc1  = (const float*)d_in[9];
    const float* Wc2  = (const float*)d_in[10];
    const float* We1  = (const float*)d_in[11];
    const float* be1  = (const float*)d_in[12];
    const float* We2  = (const float*)d_in[13];

    const int E = in_sizes[3];
    const int N = in_sizes[0] / ND;

    // workspace layout
    float* h_agg = (float*)d_ws;                           // N*ND
    float* x_agg = h_agg + (size_t)N * ND;                 // N*3
    float* bn1p  = x_agg + (size_t)N * 3;                  // HD
    float* bc1p  = bn1p + HD;                              // HD
    __hip_bfloat16* hb   = (__hip_bfloat16*)(bc1p + HD);   // N*ND bf16
    __hip_bfloat16* Wn1s = hb + (size_t)N * ND;            // 81920
    __hip_bfloat16* Wc1s = Wn1s + 81920;                   // 81920
    __hip_bfloat16* Wn2s = Wc1s + 81920;                   // 32768
    int*   cnt   = (int*)(Wn2s + 32768);                   // N
    int*   bsum  = cnt + N;                                // 256
    int*   head  = bsum + 256;                             // N
    int*   ssrc  = head + N;                               // E
    int*   sdst  = ssrc + E;                               // E
    float* sdist = (float*)(sdst + E);                     // E
    __hip_bfloat16* Q = (__hip_bfloat16*)(sdist + E);      // N*512 bf16 (51.2 MB)

    hipMemsetAsync(d_ws, 0, ((size_t)N * ND + (size_t)N * 3) * sizeof(float), stream);
    hipMemsetAsync(cnt, 0, (size_t)N * sizeof(int), stream);

    const int nbN = (N + 255) / 256;
    const int nbE = (E + 255) / 256;

    s_hist   <<<nbE, 256, 0, stream>>>(eidx, cnt, E);
    s_scan1  <<<nbN, 256, 0, stream>>>(cnt, bsum, N);
    s_scan2  <<<1,   256, 0, stream>>>(bsum, nbN);
    s_scan3  <<<nbN, 256, 0, stream>>>(cnt, bsum, head, N);
    s_scatter<<<nbE, 256, 0, stream>>>(eidx, dist, head, ssrc, sdst, sdist, E);

    int nh = N * ND;
    prep_h<<<(nh + 255) / 256, 256, 0, stream>>>(h, hb, nh);
    prep_w<<<768, 256, 0, stream>>>(Wn1, Wc1, Wn2, We2, Wn1s, Wc1s, Wn2s);
    prep_bias<<<2, 256, 0, stream>>>(bn1, bc1, Wn1, Wc1, (const float*)d_in[14], bn1p, bc1p);

    dim3 qgrid((N + 63) / 64, 2);
    prep_q<<<qgrid, 256, 0, stream>>>(hb, Wn1s, Wc1s, Q, N);

    egnn_main<<<(E + ET - 1) / ET, 256, 0, stream>>>(
        hb, x, ssrc, sdst, sdist, Wn1s, Wc1s, Wn2s, Q, bn1p, bc1p, bn2, Wc2,
        We1, be1, h_agg, x_agg, E);

    int total = N * ND + N * 3;
    egnn_finalize<<<(total + 255) / 256, 256, 0, stream>>>(
        h, x, h_agg, x_agg, (float*)d_out, N);
}

// Round 6
// 787.384 us; speedup vs baseline: 9.6157x; 1.1402x over previous
//
#include <hip/hip_runtime.h>
#include <hip/hip_bf16.h>

typedef __attribute__((ext_vector_type(8))) short bf16x8;
typedef __attribute__((ext_vector_type(4))) float f32x4;

constexpr int ND = 128;   // node dim
constexpr int HD = 256;   // hidden dim
constexpr int ED = 64;    // edge dim
constexpr int ET = 64;    // edges per block tile
constexpr int MPn = 200;  // m pitch bf16 (400B -> 2-way-free banks for A-frag b128 reads)
constexpr int HP  = 264;  // hid pitch bf16 (528B)
constexpr int MSGP = 132; // msg pitch f32 (528B)

__device__ __forceinline__ float silu_f(float v) { return v / (1.0f + __expf(-v)); }
__device__ __forceinline__ __hip_bfloat16 f2b(float v) { return __float2bfloat16(v); }
__device__ __forceinline__ unsigned short f2bu(float v) {
    __hip_bfloat16 b = __float2bfloat16(v);
    return *(unsigned short*)&b;
}
__device__ __forceinline__ float bu2f(unsigned short u) {
    unsigned int t = ((unsigned int)u) << 16;
    return __uint_as_float(t);
}

// ---------- prep: h -> bf16 ----------
__global__ __launch_bounds__(256) void prep_h(const float* __restrict__ h,
                                              __hip_bfloat16* __restrict__ hb, int n) {
    int i = blockIdx.x * 256 + threadIdx.x;
    if (i < n) hb[i] = f2b(h[i]);
}

// ---------- prep: weights -> bf16, swizzled to B-fragment order ----------
__global__ __launch_bounds__(256) void prep_w(
    const float* __restrict__ Wn1, const float* __restrict__ Wc1,
    const float* __restrict__ Wn2, const float* __restrict__ We2,
    __hip_bfloat16* __restrict__ Wn1s, __hip_bfloat16* __restrict__ Wc1s,
    __hip_bfloat16* __restrict__ Wn2s)
{
    int id = blockIdx.x * 256 + threadIdx.x;
    if (id < 163840) {                      // Wn1s / Wc1s: 10 ks * 16 nt * 64 * 8
        int e = id;
        const float* W = Wn1; __hip_bfloat16* out = Wn1s;
        if (id >= 81920) { e -= 81920; W = Wc1; out = Wc1s; }
        int j = e & 7, lane = (e >> 3) & 63, nt = (e >> 9) & 15, ks = e >> 13;
        int k = ks * 32 + (lane >> 4) * 8 + j;
        int n = nt * 16 + (lane & 15);
        float v;
        if (k < 2 * ND) v = W[k * HD + n];
        else {
            int t = k - 2 * ND; v = 0.f;
            for (int u = 0; u < ED; ++u) v += We2[t * ED + u] * W[(2 * ND + u) * HD + n];
        }
        out[e] = f2b(v);
    } else if (id < 196608) {               // Wn2s: 8 ks * 8 nt * 64 * 8
        int e = id - 163840;
        int j = e & 7, lane = (e >> 3) & 63, nt = (e >> 9) & 7, ks = e >> 12;
        int k = ks * 32 + (lane >> 4) * 8 + j;
        int n = nt * 16 + (lane & 15);
        Wn2s[e] = f2b(Wn2[k * ND + n]);
    }
}

// ---------- prep: fold be2 @ W[256:320,:] into biases ----------
__global__ __launch_bounds__(256) void prep_bias(
    const float* __restrict__ bn1, const float* __restrict__ bc1,
    const float* __restrict__ Wn1, const float* __restrict__ Wc1,
    const float* __restrict__ be2,
    float* __restrict__ bn1p, float* __restrict__ bc1p)
{
    int n = blockIdx.x * 256 + threadIdx.x;
    if (n < HD) {
        float v = bn1[n];
        for (int t = 0; t < ED; ++t) v += be2[t] * Wn1[(2 * ND + t) * HD + n];
        bn1p[n] = v;
    } else if (n < 2 * HD) {
        int m = n - HD;
        float v = bc1[m];
        for (int t = 0; t < ED; ++t) v += be2[t] * Wc1[(2 * ND + t) * HD + m];
        bc1p[m] = v;
    }
}

// ---------- prep: Q = h @ [Wn1_mid | Wc1_mid], stored in C-fragment packed order ----------
// Q element (node, pass, wv, lc, nti) at ((node*2+pass)*64 + wv*16 + lc)*4 + nti (ushort bf16 bits)
__global__ __launch_bounds__(256) void prep_q(
    const __hip_bfloat16* __restrict__ hb,
    const __hip_bfloat16* __restrict__ Wn1s,
    const __hip_bfloat16* __restrict__ Wc1s,
    unsigned short* __restrict__ Q, int N)
{
    __shared__ __align__(16) __hip_bfloat16 a_sh[64 * 136];  // pitch 272B
    const int tid = threadIdx.x;
    const int lane = tid & 63, wv = tid >> 6;
    const int q = lane >> 4, lc = lane & 15;
    const int row0 = blockIdx.x * 64;

    for (int i = tid; i < 64 * 16; i += 256) {
        int r = i >> 4, piece = i & 15;
        int node = min(row0 + r, N - 1);
        uint4 v = ((const uint4*)(hb + (size_t)node * ND))[piece];
        *((uint4*)((char*)a_sh + r * 272 + piece * 16)) = v;
    }
    __syncthreads();

    for (int pass = 0; pass < 2; ++pass) {
        const __hip_bfloat16* Ws = pass ? Wc1s : Wn1s;
        f32x4 acc[4][4];
        #pragma unroll
        for (int rt = 0; rt < 4; ++rt)
            #pragma unroll
            for (int nti = 0; nti < 4; ++nti) acc[rt][nti] = (f32x4){0.f, 0.f, 0.f, 0.f};

        for (int ks = 0; ks < 4; ++ks) {
            bf16x8 a[4];
            #pragma unroll
            for (int rt = 0; rt < 4; ++rt)
                a[rt] = *(const bf16x8*)&a_sh[(rt * 16 + lc) * 136 + ks * 32 + q * 8];
            #pragma unroll
            for (int nti = 0; nti < 4; ++nti) {
                bf16x8 b = *(const bf16x8*)&Ws[(((ks + 4) * 16 + wv * 4 + nti) * 64 + lane) * 8];
                #pragma unroll
                for (int rt = 0; rt < 4; ++rt)
                    acc[rt][nti] = __builtin_amdgcn_mfma_f32_16x16x32_bf16(a[rt], b, acc[rt][nti], 0, 0, 0);
            }
        }
        #pragma unroll
        for (int rt = 0; rt < 4; ++rt)
            #pragma unroll
            for (int r = 0; r < 4; ++r) {
                int node = row0 + rt * 16 + q * 4 + r;
                if (node < N) {
                    ushort4 us;
                    us.x = f2bu(acc[rt][0][r]); us.y = f2bu(acc[rt][1][r]);
                    us.z = f2bu(acc[rt][2][r]); us.w = f2bu(acc[rt][3][r]);
                    ((ushort4*)Q)[((size_t)node * 2 + pass) * 64 + wv * 16 + lc] = us;
                }
            }
    }
}

// ---------- counting sort by dst ----------
__global__ __launch_bounds__(256) void s_hist(const int* __restrict__ eidx,
                                              int* __restrict__ cnt, int E) {
    int e = blockIdx.x * 256 + threadIdx.x;
    if (e < E) atomicAdd(&cnt[eidx[E + e]], 1);
}

__global__ __launch_bounds__(256) void s_scan1(const int* __restrict__ cnt,
                                               int* __restrict__ bsum, int N) {
    __shared__ int sh[256];
    int i = blockIdx.x * 256 + threadIdx.x;
    sh[threadIdx.x] = (i < N) ? cnt[i] : 0;
    __syncthreads();
    for (int s = 128; s > 0; s >>= 1) {
        if (threadIdx.x < s) sh[threadIdx.x] += sh[threadIdx.x + s];
        __syncthreads();
    }
    if (threadIdx.x == 0) bsum[blockIdx.x] = sh[0];
}

__global__ __launch_bounds__(256) void s_scan2(int* __restrict__ bsum, int nb) {
    __shared__ int sh[256];
    int t = threadIdx.x;
    int orig = (t < nb) ? bsum[t] : 0;
    sh[t] = orig;
    __syncthreads();
    for (int off = 1; off < 256; off <<= 1) {
        int u = (t >= off) ? sh[t - off] : 0;
        __syncthreads();
        sh[t] += u;
        __syncthreads();
    }
    if (t < nb) bsum[t] = sh[t] - orig;   // exclusive
}

__global__ __launch_bounds__(256) void s_scan3(const int* __restrict__ cnt,
                                               const int* __restrict__ bsum,
                                               int* __restrict__ head, int N) {
    __shared__ int sh[256];
    int t = threadIdx.x, i = blockIdx.x * 256 + t;
    int v = (i < N) ? cnt[i] : 0;
    sh[t] = v;
    __syncthreads();
    for (int off = 1; off < 256; off <<= 1) {
        int u = (t >= off) ? sh[t - off] : 0;
        __syncthreads();
        sh[t] += u;
        __syncthreads();
    }
    if (i < N) head[i] = bsum[blockIdx.x] + sh[t] - v;  // exclusive prefix
}

__global__ __launch_bounds__(256) void s_scatter(
    const int* __restrict__ eidx, const float* __restrict__ dist,
    int* __restrict__ head, int4* __restrict__ sedge, int E)
{
    int e = blockIdx.x * 256 + threadIdx.x;
    if (e < E) {
        int d = eidx[E + e];
        int pos = atomicAdd(&head[d], 1);
        int4 v; v.x = eidx[e]; v.y = d; v.z = __float_as_int(dist[e]); v.w = 0;
        sedge[pos] = v;
    }
}

// ---------- main fused edge kernel (edges sorted by dst; dst factored via Q) ----------
__global__ __launch_bounds__(256, 4) void egnn_main(
    const __hip_bfloat16* __restrict__ hb,
    const float* __restrict__ x,
    const int4* __restrict__ sedge,
    const __hip_bfloat16* __restrict__ Wn1s,
    const __hip_bfloat16* __restrict__ Wc1s,
    const __hip_bfloat16* __restrict__ Wn2s,
    const unsigned short* __restrict__ Q,
    const float* __restrict__ bn1p, const float* __restrict__ bc1p,
    const float* __restrict__ bn2,  const float* __restrict__ Wc2,
    const float* __restrict__ We1,  const float* __restrict__ be1,
    float* __restrict__ h_agg, float* __restrict__ x_agg,
    int E)
{
    // overlay: m [64][MPn] bf16 (25.6KB) -> hid [64][HP] bf16 (33.8KB) -> msg [64][MSGP] f32 (33.8KB)
    __shared__ __align__(16) unsigned char smem[ET * HP * 2];
    __shared__ float dir_sh[ET * 3];
    __shared__ float coordw_sh[ET];
    __shared__ float dist_sh[ET];
    __shared__ int   sidx[ET], didx[ET];

    __hip_bfloat16* m_sh = (__hip_bfloat16*)smem;

    const int tid  = threadIdx.x;
    const int lane = tid & 63;
    const int wv   = tid >> 6;
    const int q    = lane >> 4;
    const int lc   = lane & 15;
    const int e0   = blockIdx.x * ET;

    if (tid < ET) {
        int e = min(e0 + tid, E - 1);
        int4 v = sedge[e];
        int s = v.x, d = v.y;
        sidx[tid] = s; didx[tid] = d;
        dist_sh[tid] = __int_as_float(v.z);
        coordw_sh[tid] = 0.f;
        #pragma unroll
        for (int c = 0; c < 3; ++c) dir_sh[tid * 3 + c] = x[s * 3 + c] - x[d * 3 + c];
    }
    __syncthreads();

    // gather h[src] -> m[:,0:128]
    for (int i = tid; i < ET * 16; i += 256) {
        int er = i >> 4, piece = i & 15;
        uint4 v = ((const uint4*)(hb + (size_t)sidx[er] * ND))[piece];
        *((uint4*)((char*)m_sh + er * (MPn * 2) + piece * 16)) = v;
    }
    // se = silu(dist*We1+be1) -> m[:,128:192]
    for (int i = tid; i < ET * ED; i += 256) {
        int er = i >> 6, j = i & 63;
        m_sh[er * MPn + ND + j] = f2b(silu_f(fmaf(dist_sh[er], We1[j], be1[j])));
    }
    __syncthreads();

    // ---- GEMM1 pass A: coord hidden = [h_src|se]@Wc' + Q[dst][coord] + bias ----
    {
        f32x4 acc[4][4];
        #pragma unroll
        for (int nti = 0; nti < 4; ++nti) {
            float b = bc1p[(wv * 4 + nti) * 16 + lc];
            #pragma unroll
            for (int rt = 0; rt < 4; ++rt) acc[rt][nti] = (f32x4){b, b, b, b};
        }
        for (int ks = 0; ks < 6; ++ks) {
            int bk = (ks < 4) ? ks : ks + 4;   // ks 4,5 -> folded se rows (orig ks 8,9)
            bf16x8 a[4];
            #pragma unroll
            for (int rt = 0; rt < 4; ++rt)
                a[rt] = *(const bf16x8*)&m_sh[(rt * 16 + lc) * MPn + ks * 32 + q * 8];
            #pragma unroll
            for (int nti = 0; nti < 4; ++nti) {
                bf16x8 b = *(const bf16x8*)&Wc1s[((bk * 16 + wv * 4 + nti) * 64 + lane) * 8];
                #pragma unroll
                for (int rt = 0; rt < 4; ++rt)
                    acc[rt][nti] = __builtin_amdgcn_mfma_f32_16x16x32_bf16(a[rt], b, acc[rt][nti], 0, 0, 0);
            }
        }
        float wcv[4];
        #pragma unroll
        for (int nti = 0; nti < 4; ++nti) wcv[nti] = Wc2[(wv * 4 + nti) * 16 + lc];
        #pragma unroll
        for (int rt = 0; rt < 4; ++rt) {
            float p[4];
            #pragma unroll
            for (int r = 0; r < 4; ++r) {
                int dd = didx[rt * 16 + q * 4 + r];
                ushort4 us = ((const ushort4*)Q)[((size_t)dd * 2 + 1) * 64 + wv * 16 + lc];
                float pv = 0.f;
                pv += silu_f(acc[rt][0][r] + bu2f(us.x)) * wcv[0];
                pv += silu_f(acc[rt][1][r] + bu2f(us.y)) * wcv[1];
                pv += silu_f(acc[rt][2][r] + bu2f(us.z)) * wcv[2];
                pv += silu_f(acc[rt][3][r] + bu2f(us.w)) * wcv[3];
                p[r] = pv;
            }
            #pragma unroll
            for (int r = 0; r < 4; ++r) {
                float v = p[r];
                v += __shfl_xor(v, 1); v += __shfl_xor(v, 2);
                v += __shfl_xor(v, 4); v += __shfl_xor(v, 8);
                if (lc == 0) atomicAdd(&coordw_sh[rt * 16 + q * 4 + r], v);
            }
        }
    }

    // ---- GEMM1 pass B: node hidden ----
    f32x4 accn[4][4];
    #pragma unroll
    for (int nti = 0; nti < 4; ++nti) {
        float b = bn1p[(wv * 4 + nti) * 16 + lc];
        #pragma unroll
        for (int rt = 0; rt < 4; ++rt) accn[rt][nti] = (f32x4){b, b, b, b};
    }
    for (int ks = 0; ks < 6; ++ks) {
        int bk = (ks < 4) ? ks : ks + 4;
        bf16x8 a[4];
        #pragma unroll
        for (int rt = 0; rt < 4; ++rt)
            a[rt] = *(const bf16x8*)&m_sh[(rt * 16 + lc) * MPn + ks * 32 + q * 8];
        #pragma unroll
        for (int nti = 0; nti < 4; ++nti) {
            bf16x8 b = *(const bf16x8*)&Wn1s[((bk * 16 + wv * 4 + nti) * 64 + lane) * 8];
            #pragma unroll
            for (int rt = 0; rt < 4; ++rt)
                accn[rt][nti] = __builtin_amdgcn_mfma_f32_16x16x32_bf16(a[rt], b, accn[rt][nti], 0, 0, 0);
        }
    }
    __syncthreads();   // all waves done reading m_sh

    // hid = silu(accn + Q[dst][node]) overlaid into smem, [64][HP] bf16
    __hip_bfloat16* hid = (__hip_bfloat16*)smem;
    #pragma unroll
    for (int rt = 0; rt < 4; ++rt) {
        #pragma unroll
        for (int r = 0; r < 4; ++r) {
            int row = rt * 16 + q * 4 + r;
            int dd = didx[row];
            ushort4 us = ((const ushort4*)Q)[(size_t)dd * 2 * 64 + wv * 16 + lc];
            hid[row * HP + (wv * 4 + 0) * 16 + lc] = f2b(silu_f(accn[rt][0][r] + bu2f(us.x)));
            hid[row * HP + (wv * 4 + 1) * 16 + lc] = f2b(silu_f(accn[rt][1][r] + bu2f(us.y)));
            hid[row * HP + (wv * 4 + 2) * 16 + lc] = f2b(silu_f(accn[rt][2][r] + bu2f(us.z)));
            hid[row * HP + (wv * 4 + 3) * 16 + lc] = f2b(silu_f(accn[rt][3][r] + bu2f(us.w)));
        }
    }
    __syncthreads();

    // ---- GEMM2: msg[64x128] = hid @ Wn2 + bn2 ----
    f32x4 acc2[4][2];
    #pragma unroll
    for (int nti = 0; nti < 2; ++nti) {
        float b = bn2[(wv * 2 + nti) * 16 + lc];
        #pragma unroll
        for (int rt = 0; rt < 4; ++rt) acc2[rt][nti] = (f32x4){b, b, b, b};
    }
    for (int ks = 0; ks < 8; ++ks) {
        bf16x8 a[4];
        #pragma unroll
        for (int rt = 0; rt < 4; ++rt)
            a[rt] = *(const bf16x8*)&hid[(rt * 16 + lc) * HP + ks * 32 + q * 8];
        #pragma unroll
        for (int nti = 0; nti < 2; ++nti) {
            bf16x8 b = *(const bf16x8*)&Wn2s[((ks * 8 + wv * 2 + nti) * 64 + lane) * 8];
            #pragma unroll
            for (int rt = 0; rt < 4; ++rt)
                acc2[rt][nti] = __builtin_amdgcn_mfma_f32_16x16x32_bf16(a[rt], b, acc2[rt][nti], 0, 0, 0);
        }
    }
    __syncthreads();   // waves done reading hid; safe to overlay msg

    float* msg = (float*)smem;
    #pragma unroll
    for (int rt = 0; rt < 4; ++rt)
        #pragma unroll
        for (int nti = 0; nti < 2; ++nti)
            #pragma unroll
            for (int r = 0; r < 4; ++r)
                msg[(rt * 16 + q * 4 + r) * MSGP + (wv * 2 + nti) * 16 + lc] = acc2[rt][nti][r];
    __syncthreads();

    // ---- segmented flush: 4 cols/thread via b128, 8-row groups ----
    {
        int c  = (tid & 31) * 4;
        int r0 = (tid >> 5) * 8;
        f32x4 run = (f32x4){0.f, 0.f, 0.f, 0.f};
        int cur = -1;
        for (int r = r0; r < r0 + 8; ++r) {
            int d = (e0 + r < E) ? didx[r] : -1;
            if (d != cur) {
                if (cur >= 0) {
                    float* dst = &h_agg[(size_t)cur * ND + c];
                    atomicAdd(dst + 0, run[0]); atomicAdd(dst + 1, run[1]);
                    atomicAdd(dst + 2, run[2]); atomicAdd(dst + 3, run[3]);
                }
                run = (f32x4){0.f, 0.f, 0.f, 0.f}; cur = d;
            }
            if (d >= 0) {
                f32x4 m4 = *(const f32x4*)&msg[r * MSGP + c];
                run += m4;
            }
        }
        if (cur >= 0) {
            float* dst = &h_agg[(size_t)cur * ND + c];
            atomicAdd(dst + 0, run[0]); atomicAdd(dst + 1, run[1]);
            atomicAdd(dst + 2, run[2]); atomicAdd(dst + 3, run[3]);
        }
    }
    if (tid < 6) {
        int c = tid % 3, r0 = (tid / 3) * 32;
        float run = 0.f; int cur = -1;
        for (int r = r0; r < r0 + 32; ++r) {
            int d = (e0 + r < E) ? didx[r] : -1;
            if (d != cur) {
                if (cur >= 0) atomicAdd(&x_agg[cur * 3 + c], run);
                run = 0.f; cur = d;
            }
            if (d >= 0) run += coordw_sh[r] * dir_sh[r * 3 + c];
        }
        if (cur >= 0) atomicAdd(&x_agg[cur * 3 + c], run);
    }
}

__global__ __launch_bounds__(256) void egnn_finalize(
    const float* __restrict__ h, const float* __restrict__ x,
    const float* __restrict__ h_agg, const float* __restrict__ x_agg,
    float* __restrict__ out, int n_nodes)
{
    int i = blockIdx.x * 256 + threadIdx.x;
    int nh = n_nodes * ND;
    int total = nh + n_nodes * 3;
    if (i < nh)       out[i] = h[i] + h_agg[i];
    else if (i < total) { int k = i - nh; out[i] = x[k] + x_agg[k]; }
}

extern "C" void kernel_launch(void* const* d_in, const int* in_sizes, int n_in,
                              void* d_out, int out_size, void* d_ws, size_t ws_size,
                              hipStream_t stream)
{
    const float* h    = (const float*)d_in[0];
    const float* x    = (const float*)d_in[1];
    const int*   eidx = (const int*)d_in[2];
    const float* dist = (const float*)d_in[3];
    const float* Wn1  = (const float*)d_in[4];
    const float* bn1  = (const float*)d_in[5];
    const float* Wn2  = (const float*)d_in[6];
    const float* bn2  = (const float*)d_in[7];
    const float* Wc1  = (const float*)d_in[8];
    const float* bc1  = (const float*)d_in[9];
    const float* Wc2  = (const float*)d_in[10];
    const float* We1  = (const float*)d_in[11];
    const float* be1  = (const float*)d_in[12];
    const float* We2  = (const float*)d_in[13];

    const int E = in_sizes[3];
    const int N = in_sizes[0] / ND;

    // workspace layout (all segments 16B-aligned)
    float* h_agg = (float*)d_ws;                           // N*ND
    float* x_agg = h_agg + (size_t)N * ND;                 // N*3
    float* bn1p  = x_agg + (size_t)N * 3;                  // HD
    float* bc1p  = bn1p + HD;                              // HD
    __hip_bfloat16* hb   = (__hip_bfloat16*)(bc1p + HD);   // N*ND bf16
    __hip_bfloat16* Wn1s = hb + (size_t)N * ND;            // 81920
    __hip_bfloat16* Wc1s = Wn1s + 81920;                   // 81920
    __hip_bfloat16* Wn2s = Wc1s + 81920;                   // 32768
    int*   cnt   = (int*)(Wn2s + 32768);                   // N
    int*   bsum  = cnt + N;                                // 256
    int*   head  = bsum + 256;                             // N
    int4*  sedge = (int4*)(head + N);                      // E int4
    unsigned short* Q = (unsigned short*)(sedge + E);      // N*512 bf16 bits

    hipMemsetAsync(d_ws, 0, ((size_t)N * ND + (size_t)N * 3) * sizeof(float), stream);
    hipMemsetAsync(cnt, 0, (size_t)N * sizeof(int), stream);

    const int nbN = (N + 255) / 256;
    const int nbE = (E + 255) / 256;

    s_hist   <<<nbE, 256, 0, stream>>>(eidx, cnt, E);
    s_scan1  <<<nbN, 256, 0, stream>>>(cnt, bsum, N);
    s_scan2  <<<1,   256, 0, stream>>>(bsum, nbN);
    s_scan3  <<<nbN, 256, 0, stream>>>(cnt, bsum, head, N);
    s_scatter<<<nbE, 256, 0, stream>>>(eidx, dist, head, sedge, E);

    int nh = N * ND;
    prep_h<<<(nh + 255) / 256, 256, 0, stream>>>(h, hb, nh);
    prep_w<<<768, 256, 0, stream>>>(Wn1, Wc1, Wn2, We2, Wn1s, Wc1s, Wn2s);
    prep_bias<<<2, 256, 0, stream>>>(bn1, bc1, Wn1, Wc1, (const float*)d_in[14], bn1p, bc1p);
    prep_q<<<(N + 63) / 64, 256, 0, stream>>>(hb, Wn1s, Wc1s, Q, N);

    egnn_main<<<(E + ET - 1) / ET, 256, 0, stream>>>(
        hb, x, sedge, Wn1s, Wc1s, Wn2s, Q, bn1p, bc1p, bn2, Wc2,
        We1, be1, h_agg, x_agg, E);

    int total = N * ND + N * 3;
    egnn_finalize<<<(total + 255) / 256, 256, 0, stream>>>(
        h, x, h_agg, x_agg, (float*)d_out, N);
}